// Round 3
// baseline (586.909 us; speedup 1.0000x reference)
//
#include <hip/hip_runtime.h>

// ---------------------------------------------------------------------------
// MultiAgentCommSystem fused kernel, v4 (critical-path restructure).
// vs v3: (1) folded weights W26=W2@Wq and WF=Wo@Wi1_bot computed in f32 by
// prep -> G5 phase and msgs LDS round-trip deleted (barriers 8->6);
// (2) softmax via MFMA row-sum of unnormalized exp(P) against all-ones B
// fragment -> zero shuffles in softmax; (3) all biases pre-converted to f32
// in ws -> single macs_main dispatch with runtime in/out dtype; (4) obs
// fragments loaded once, reused in G6; pinned weight prefetches.
// ---------------------------------------------------------------------------

typedef __attribute__((ext_vector_type(8))) short bf16x8;
typedef __attribute__((ext_vector_type(4))) float f32x4;
typedef __attribute__((ext_vector_type(16))) float f32x16;

#define MFMA16(a, b, c) __builtin_amdgcn_mfma_f32_16x16x32_bf16((a), (b), (c), 0, 0, 0)
#define MFMA32(a, b, c) __builtin_amdgcn_mfma_f32_32x32x16_bf16((a), (b), (c), 0, 0, 0)

__device__ __forceinline__ float b2f(short s) {
    union { unsigned u; float f; } x;
    x.u = ((unsigned)(unsigned short)s) << 16;
    return x.f;
}
__device__ __forceinline__ short f2b(float f) {
    union { float f; unsigned u; } x;
    x.f = f;
    unsigned r = (x.u + 0x7FFFu + ((x.u >> 16) & 1u)) >> 16;
    return (short)r;
}
__device__ __forceinline__ float ldw(const void* p, long i, bool bf) {
    return bf ? b2f(((const short*)p)[i]) : ((const float*)p)[i];
}
__device__ __forceinline__ bf16x8 ld8rt(const void* p, long i, bool bf) {
    if (bf) return *(const bf16x8*)((const short*)p + i);
    const float4* f = (const float4*)((const float*)p + i);
    float4 a = f[0], c = f[1];
    bf16x8 r;
    r[0] = f2b(a.x); r[1] = f2b(a.y); r[2] = f2b(a.z); r[3] = f2b(a.w);
    r[4] = f2b(c.x); r[5] = f2b(c.y); r[6] = f2b(c.z); r[7] = f2b(c.w);
    return r;
}

// ---- LDS layout (shorts), total 26624 shorts = 53248 B (3 blocks/CU) ----
// U @0: h[64][136]=8704 (G1..G2') | P 4x[32][72]=9216 (attn) | z[64][264]=16896 (G6..G7)
// Q 4x[64][16]=4096 @9216 | K 4x[64][16]=4096 @13312
// VT 4x[16][72]=4608 @17408 | lnred/munr overlay VT in G6
// ctx [64][72]=4608 @22016
#define P_S   0
#define H_S   0
#define Z_S   0
#define Q2_S  9216
#define K2_S  13312
#define VT_S  17408
#define LN_S  17408
#define MU_S  18432
#define CTX_S 22016
#define SMEM_SHORTS 26624
#define HP 136
#define MP 72
#define ZP 264
#define PP 72
#define VP 72

// ---- ws layout (shorts): flag 128 | wt 131072 | f32 biases 2560 | obs_bf ----
#define WT1_OFF   0       // [128][128] K=128
#define WT2_OFF   16384   // [64][128]
#define WT26_OFF  24576   // [192][128]  (W2@Wq fold, K=128)
#define WTI1_OFF  49152   // [256][128]  (Wi1 obs part, K=128)
#define WTF_OFF   81920   // [256][64]   (Wo@Wi1_bot fold, K=64)
#define WTI2_OFF  98304   // [128][256]
#define WT_TOTAL  131072
// f32 bias area (offsets in floats)
#define FB_B26 0      // 192: ipb + b2@Wq
#define FB_BI  192    // 256: ib1 + ob@Wi1_bot
#define FB_EB1 448    // 128
#define FB_EB2 576    // 64
#define FB_LG  640    // 256
#define FB_LB  896    // 256
#define FB_IB2 1152   // 128
#define FB_TOTAL 1280
#define OBS_ELEMS 33554432L   // 4096*64*128
#define WS_NEEDED ((unsigned long)(128 + WT_TOTAL + 2 * FB_TOTAL + OBS_ELEMS) * 2UL)

// prep: detect dtype, transpose + fold weights (f32 accum), convert biases to
// f32, optionally convert obs -> bf16.
template<bool DO_CONV>
__global__ void prep(const void* __restrict__ obs,
                     const void* __restrict__ w1, const void* __restrict__ w2,
                     const void* __restrict__ wq, const void* __restrict__ wo,
                     const void* __restrict__ wi1, const void* __restrict__ wi2,
                     const void* __restrict__ eb1, const void* __restrict__ eb2,
                     const void* __restrict__ ipb, const void* __restrict__ ob,
                     const void* __restrict__ ib1, const void* __restrict__ lg,
                     const void* __restrict__ lb,  const void* __restrict__ ib2,
                     int* __restrict__ flag, short* __restrict__ wt,
                     float* __restrict__ fb, short* __restrict__ obs_bf) {
    const unsigned short* o16 = (const unsigned short*)obs;
    int lane = threadIdx.x & 63;
    int cnt = 0;
    for (int i = lane; i < 512; i += 64) {
        unsigned e = (o16[i] >> 7) & 0xFFu;
        cnt += (e == 0u || (e >= 80u && e <= 140u)) ? 1 : 0;
    }
#pragma unroll
    for (int off = 1; off < 64; off <<= 1) cnt += __shfl_xor(cnt, off);
    const bool bf = (cnt >= 480);
    if (blockIdx.x == 0 && threadIdx.x == 0) *flag = bf ? 1 : 0;

    long id = (long)blockIdx.x * 256 + threadIdx.x;
    if (id < 16384) {
        int n = (int)id >> 7, k = (int)id & 127;
        wt[WT1_OFF + id] = f2b(ldw(w1, k * 128 + n, bf));
    } else if (id < 24576) {
        int loc = (int)id - 16384, n = loc >> 7, k = loc & 127;
        wt[WT2_OFF + loc] = f2b(ldw(w2, k * 64 + n, bf));
    } else if (id < 49152) {
        int loc = (int)id - 24576, n = loc >> 7, k = loc & 127;
        float s = 0.f;
        for (int j = 0; j < 64; ++j) s += ldw(w2, k * 64 + j, bf) * ldw(wq, j * 192 + n, bf);
        wt[WT26_OFF + loc] = f2b(s);
    } else if (id < 81920) {
        int loc = (int)id - 49152, n = loc >> 7, k = loc & 127;
        wt[WTI1_OFF + loc] = f2b(ldw(wi1, k * 256 + n, bf));
    } else if (id < 98304) {
        int loc = (int)id - 81920, n = loc >> 6, c = loc & 63;
        float s = 0.f;
        for (int m = 0; m < 64; ++m) s += ldw(wo, c * 64 + m, bf) * ldw(wi1, (128 + m) * 256 + n, bf);
        wt[WTF_OFF + loc] = f2b(s);
    } else if (id < 131072) {
        int loc = (int)id - 98304, n = loc >> 8, k = loc & 255;
        wt[WTI2_OFF + loc] = f2b(ldw(wi2, k * 128 + n, bf));
    } else if (id < 131264) {
        int n = (int)id - 131072;
        float s = ldw(ipb, n, bf);
        for (int j = 0; j < 64; ++j) s += ldw(eb2, j, bf) * ldw(wq, j * 192 + n, bf);
        fb[FB_B26 + n] = s;
    } else if (id < 131520) {
        int n = (int)id - 131264;
        float s = ldw(ib1, n, bf);
        for (int m = 0; m < 64; ++m) s += ldw(ob, m, bf) * ldw(wi1, (128 + m) * 256 + n, bf);
        fb[FB_BI + n] = s;
    } else if (id < 132352) {
        int j = (int)id - 131520;
        float v; int d;
        if (j < 128)      { v = ldw(eb1, j, bf);       d = FB_EB1 + j; }
        else if (j < 192) { v = ldw(eb2, j - 128, bf); d = FB_EB2 + j - 128; }
        else if (j < 448) { v = ldw(lg, j - 192, bf);  d = FB_LG + j - 192; }
        else if (j < 704) { v = ldw(lb, j - 448, bf);  d = FB_LB + j - 448; }
        else              { v = ldw(ib2, j - 704, bf); d = FB_IB2 + j - 704; }
        fb[d] = v;
    } else if (DO_CONV && !bf) {
        long base = (id - 132352) * 8;
        if (base < OBS_ELEMS) {
            const float4* f = (const float4*)((const float*)obs + base);
            float4 a = f[0], c = f[1];
            bf16x8 r;
            r[0] = f2b(a.x); r[1] = f2b(a.y); r[2] = f2b(a.z); r[3] = f2b(a.w);
            r[4] = f2b(c.x); r[5] = f2b(c.y); r[6] = f2b(c.z); r[7] = f2b(c.w);
            *(bf16x8*)(obs_bf + base) = r;
        }
    }
}

template<bool OBSBF>
__global__ __launch_bounds__(256, 3)
void macs_main(const void* __restrict__ obs, const int* __restrict__ flag,
               const short* __restrict__ wt, const float* __restrict__ fb,
               const short* __restrict__ obs_bf, void* __restrict__ out) {
    __shared__ __align__(16) short smem[SMEM_SHORTS];
    const int tid = threadIdx.x;
    const int w = tid >> 6;
    const int lane = tid & 63;
    const int q = lane >> 4;
    const int t = lane & 15;
    const int l31 = lane & 31;
    const int hi = lane >> 5;
    const int b = blockIdx.x;
    const long obase = (long)b * 64 * 128;
    const bool inbf = (*flag != 0);
    const bool f32out = !inbf;
    const short* osrc = OBSBF ? (inbf ? (const short*)obs : obs_bf) : (const short*)0;

    // obs fragments: loaded once, used by G1 and G6.
    bf16x8 oa[4][4];
#pragma unroll
    for (int ks = 0; ks < 4; ++ks)
#pragma unroll
        for (int mt = 0; mt < 4; ++mt) {
            long idx = obase + (mt * 16 + t) * 128 + ks * 32 + q * 8;
            oa[ks][mt] = OBSBF ? *(const bf16x8*)(osrc + idx) : ld8rt(obs, idx, inbf);
        }

    bf16x8 w2p[4];        // WT2 frags, prefetched in G1 for G2'
    bf16x8 wi1p[2][4];    // WTI1 ks0-1 frags, prefetched in attn for G6
    bf16x8 w2pp[8][2];    // WTI2 frags, prefetched in G6 for G7

    // ---- G1: h = relu(obs @ W1 + eb1)   M64 K128 N128
    {
        f32x4 acc[4][2] = {};
        const short* wt1p = wt + WT1_OFF;
#pragma unroll
        for (int ks = 0; ks < 4; ++ks) {
            bf16x8 bb[2];
#pragma unroll
            for (int tj = 0; tj < 2; ++tj)
                bb[tj] = *(const bf16x8*)(wt1p + (w * 32 + tj * 16 + t) * 128 + ks * 32 + q * 8);
#pragma unroll
            for (int mt = 0; mt < 4; ++mt)
#pragma unroll
                for (int tj = 0; tj < 2; ++tj)
                    acc[mt][tj] = MFMA16(oa[ks][mt], bb[tj], acc[mt][tj]);
        }
        // pinned prefetch: G2' msgs weights
        {
            const short* wt2 = wt + WT2_OFF;
#pragma unroll
            for (int ks = 0; ks < 4; ++ks)
                w2p[ks] = *(const bf16x8*)(wt2 + (w * 16 + t) * 128 + ks * 32 + q * 8);
            __builtin_amdgcn_sched_barrier(0);
        }
        short* hs = smem + H_S;
#pragma unroll
        for (int tj = 0; tj < 2; ++tj) {
            int c = w * 32 + tj * 16 + t;
            float bias = fb[FB_EB1 + c];
#pragma unroll
            for (int mt = 0; mt < 4; ++mt)
#pragma unroll
                for (int i = 0; i < 4; ++i)
                    hs[(mt * 16 + q * 4 + i) * HP + c] = f2b(fmaxf(acc[mt][tj][i] + bias, 0.f));
        }
    }
    __syncthreads();  // S1: h visible

    // ---- G2': msgs = h@W2 + eb2 -> global only;  qkv = h@W26 + b26 -> LDS
    {
        const short* hs = smem + H_S;
        const long msgs_base = 33554432L;  // 4096*64*128
        // msgs
        f32x4 am[4] = {};
#pragma unroll
        for (int ks = 0; ks < 4; ++ks) {
            bf16x8 a[4];
#pragma unroll
            for (int mt = 0; mt < 4; ++mt)
                a[mt] = *(const bf16x8*)(hs + (mt * 16 + t) * HP + ks * 32 + q * 8);
#pragma unroll
            for (int mt = 0; mt < 4; ++mt)
                am[mt] = MFMA16(a[mt], w2p[ks], am[mt]);
        }
        float mb = fb[FB_EB2 + w * 16 + t];
        if (f32out) {
#pragma unroll
            for (int mt = 0; mt < 4; ++mt)
#pragma unroll
                for (int i = 0; i < 4; ++i)
                    ((float*)out)[msgs_base + ((long)b * 64 + mt * 16 + q * 4 + i) * 64 + w * 16 + t] = am[mt][i] + mb;
        } else {
#pragma unroll
            for (int mt = 0; mt < 4; ++mt)
#pragma unroll
                for (int i = 0; i < 4; ++i)
                    ((short*)out)[msgs_base + ((long)b * 64 + mt * 16 + q * 4 + i) * 64 + w * 16 + t] = f2b(am[mt][i] + mb);
        }
        // qkv (K=128 via fold)
        f32x4 aq[4][3] = {};
        const short* w26 = wt + WT26_OFF;
#pragma unroll
        for (int ks = 0; ks < 4; ++ks) {
            bf16x8 a[4], bb[3];
#pragma unroll
            for (int mt = 0; mt < 4; ++mt)
                a[mt] = *(const bf16x8*)(hs + (mt * 16 + t) * HP + ks * 32 + q * 8);
#pragma unroll
            for (int tj = 0; tj < 3; ++tj)
                bb[tj] = *(const bf16x8*)(w26 + (w * 48 + tj * 16 + t) * 128 + ks * 32 + q * 8);
#pragma unroll
            for (int mt = 0; mt < 4; ++mt)
#pragma unroll
                for (int tj = 0; tj < 3; ++tj)
                    aq[mt][tj] = MFMA16(a[mt], bb[tj], aq[mt][tj]);
        }
#pragma unroll
        for (int tj = 0; tj < 3; ++tj) {
            int c = w * 48 + tj * 16 + t;
            float bias = fb[FB_B26 + c];
            int sec = c >> 6;
            int head = (c >> 4) & 3;
            float scale = (sec == 0) ? 0.25f : 1.0f;
#pragma unroll
            for (int mt = 0; mt < 4; ++mt)
#pragma unroll
                for (int i = 0; i < 4; ++i) {
                    int r = mt * 16 + q * 4 + i;
                    short bv = f2b((aq[mt][tj][i] + bias) * scale);
                    int idx;
                    if (sec == 0)      idx = Q2_S + head * 1024 + r * 16 + t;
                    else if (sec == 1) idx = K2_S + head * 1024 + r * 16 + t;
                    else               idx = VT_S + head * 1152 + t * VP + r;
                    smem[idx] = bv;
                }
        }
    }
    __syncthreads();  // S3: qkv visible

    // ---- Attention: 2 passes x 2 heads; wave = (head-slot w>>1, row-half w&1)
    // Unnormalized exp(P) -> LDS; row-sum via MFMA against all-ones B frag;
    // normalize ctx with rcp. No shuffles, no attn barriers.
    {
        const int rh = w & 1;
        short* Pq = smem + P_S + w * 2304;  // [32][PP] per-wave private
        short* cs = smem + CTX_S;
        bf16x8 ones = { (short)0x3F80, (short)0x3F80, (short)0x3F80, (short)0x3F80,
                        (short)0x3F80, (short)0x3F80, (short)0x3F80, (short)0x3F80 };
#pragma unroll
        for (int p = 0; p < 2; ++p) {
            const int hd = p * 2 + (w >> 1);
            const short* qh = smem + Q2_S + hd * 1024;
            const short* kh = smem + K2_S + hd * 1024;
            const short* vh = smem + VT_S + hd * 1152;
            f32x16 sc0 = {}, sc1 = {};
            {
                bf16x8 aq  = *(const bf16x8*)(qh + (rh * 32 + l31) * 16 + hi * 8);
                bf16x8 bk0 = *(const bf16x8*)(kh + l31 * 16 + hi * 8);
                bf16x8 bk1 = *(const bf16x8*)(kh + (32 + l31) * 16 + hi * 8);
                sc0 = MFMA32(aq, bk0, sc0);
                sc1 = MFMA32(aq, bk1, sc1);
            }
#pragma unroll
            for (int i = 0; i < 16; ++i) {
                int lr = (i & 3) + 8 * (i >> 2) + 4 * hi;
                Pq[lr * PP + l31]      = f2b(__expf(sc0[i]));
                Pq[lr * PP + 32 + l31] = f2b(__expf(sc1[i]));
            }
            f32x4 cx[2] = {}, sm[2] = {};
#pragma unroll
            for (int ks = 0; ks < 2; ++ks) {
                bf16x8 bb = *(const bf16x8*)(vh + t * VP + ks * 32 + q * 8);
                bf16x8 a0 = *(const bf16x8*)(Pq + t * PP + ks * 32 + q * 8);
                bf16x8 a1 = *(const bf16x8*)(Pq + (16 + t) * PP + ks * 32 + q * 8);
                cx[0] = MFMA16(a0, bb, cx[0]);
                cx[1] = MFMA16(a1, bb, cx[1]);
                sm[0] = MFMA16(a0, ones, sm[0]);
                sm[1] = MFMA16(a1, ones, sm[1]);
            }
#pragma unroll
            for (int mt = 0; mt < 2; ++mt)
#pragma unroll
                for (int i = 0; i < 4; ++i) {
                    float inv = __builtin_amdgcn_rcpf(sm[mt][i]);
                    cs[(rh * 32 + mt * 16 + q * 4 + i) * MP + hd * 16 + t] = f2b(cx[mt][i] * inv);
                }
        }
        // pinned prefetch: G6 obs-part weights, first 2 k-slices
        {
            const short* wti1 = wt + WTI1_OFF;
#pragma unroll
            for (int ks = 0; ks < 2; ++ks)
#pragma unroll
                for (int tj = 0; tj < 4; ++tj)
                    wi1p[ks][tj] = *(const bf16x8*)(wti1 + (w * 64 + tj * 16 + t) * 128 + ks * 32 + q * 8);
            __builtin_amdgcn_sched_barrier(0);
        }
    }
    __syncthreads();  // S4: ctx visible

    // ---- G6: z = obs@Wi1_top + ctx@WF + bI, LayerNorm, relu   M64 K192 N256
    {
        f32x4 acc[4][4] = {};
        const short* wti1 = wt + WTI1_OFF;
        const short* wtf  = wt + WTF_OFF;
        const short* cs = smem + CTX_S;
        // obs part (K=128), oa reused from G1
#pragma unroll
        for (int ks = 0; ks < 4; ++ks) {
            bf16x8 bb[4];
            if (ks < 2) {
#pragma unroll
                for (int tj = 0; tj < 4; ++tj) bb[tj] = wi1p[ks][tj];
            } else {
#pragma unroll
                for (int tj = 0; tj < 4; ++tj)
                    bb[tj] = *(const bf16x8*)(wti1 + (w * 64 + tj * 16 + t) * 128 + ks * 32 + q * 8);
            }
#pragma unroll
            for (int mt = 0; mt < 4; ++mt)
#pragma unroll
                for (int tj = 0; tj < 4; ++tj)
                    acc[mt][tj] = MFMA16(oa[ks][mt], bb[tj], acc[mt][tj]);
        }
        // ctx part (K=64, folded)
#pragma unroll
        for (int ks = 0; ks < 2; ++ks) {
            bf16x8 a[4], bb[4];
#pragma unroll
            for (int mt = 0; mt < 4; ++mt)
                a[mt] = *(const bf16x8*)(cs + (mt * 16 + t) * MP + ks * 32 + q * 8);
#pragma unroll
            for (int tj = 0; tj < 4; ++tj)
                bb[tj] = *(const bf16x8*)(wtf + (w * 64 + tj * 16 + t) * 64 + ks * 32 + q * 8);
#pragma unroll
            for (int mt = 0; mt < 4; ++mt)
#pragma unroll
                for (int tj = 0; tj < 4; ++tj)
                    acc[mt][tj] = MFMA16(a[mt], bb[tj], acc[mt][tj]);
        }
#pragma unroll
        for (int tj = 0; tj < 4; ++tj) {
            float bias = fb[FB_BI + w * 64 + tj * 16 + t];
#pragma unroll
            for (int mt = 0; mt < 4; ++mt)
#pragma unroll
                for (int i = 0; i < 4; ++i) acc[mt][tj][i] += bias;
        }
        float2* lnred = (float2*)(smem + LN_S);  // overlays dead VT
#pragma unroll
        for (int mt = 0; mt < 4; ++mt)
#pragma unroll
            for (int i = 0; i < 4; ++i) {
                float s = 0.f, s2 = 0.f;
#pragma unroll
                for (int tj = 0; tj < 4; ++tj) {
                    float v = acc[mt][tj][i];
                    s += v;
                    s2 += v * v;
                }
#pragma unroll
                for (int off = 1; off < 16; off <<= 1) {
                    s += __shfl_xor(s, off);
                    s2 += __shfl_xor(s2, off);
                }
                if (t == 0) {
                    float2 p; p.x = s; p.y = s2;
                    lnred[(mt * 16 + q * 4 + i) * 4 + w] = p;
                }
            }
        __syncthreads();  // S6: lnred visible
        float2* munr = (float2*)(smem + MU_S);
        if (tid < 64) {
            float S = 0.f, S2 = 0.f;
#pragma unroll
            for (int j = 0; j < 4; ++j) {
                float2 p = lnred[tid * 4 + j];
                S += p.x;
                S2 += p.y;
            }
            float mu = S * (1.f / 256.f);
            float var = S2 * (1.f / 256.f) - mu * mu;
            float2 m; m.x = mu; m.y = rsqrtf(fmaxf(var, 0.f) + 1e-5f);
            munr[tid] = m;
        }
        __syncthreads();  // S7: munr visible
        // pinned prefetch: G7 weights
        {
            const short* wti2 = wt + WTI2_OFF;
#pragma unroll
            for (int ks = 0; ks < 8; ++ks)
#pragma unroll
                for (int tj = 0; tj < 2; ++tj)
                    w2pp[ks][tj] = *(const bf16x8*)(wti2 + (w * 32 + tj * 16 + t) * 256 + ks * 32 + q * 8);
            __builtin_amdgcn_sched_barrier(0);
        }
        short* zs = smem + Z_S;  // overlays P/Q/K (all dead)
        float gv[4], bv[4];
#pragma unroll
        for (int tj = 0; tj < 4; ++tj) {
            gv[tj] = fb[FB_LG + w * 64 + tj * 16 + t];
            bv[tj] = fb[FB_LB + w * 64 + tj * 16 + t];
        }
#pragma unroll
        for (int mt = 0; mt < 4; ++mt)
#pragma unroll
            for (int i = 0; i < 4; ++i) {
                int r = mt * 16 + q * 4 + i;
                float2 mr = munr[r];
#pragma unroll
                for (int tj = 0; tj < 4; ++tj) {
                    float v = (acc[mt][tj][i] - mr.x) * mr.y * gv[tj] + bv[tj];
                    zs[r * ZP + w * 64 + tj * 16 + t] = f2b(fmaxf(v, 0.f));
                }
            }
    }
    __syncthreads();  // S8: z visible

    // ---- G7: enriched = relu_z @ Wi2 + ib2   M64 K256 N128
    {
        f32x4 acc[4][2] = {};
        const short* zs = smem + Z_S;
#pragma unroll
        for (int ks = 0; ks < 8; ++ks) {
            bf16x8 a[4];
#pragma unroll
            for (int mt = 0; mt < 4; ++mt)
                a[mt] = *(const bf16x8*)(zs + (mt * 16 + t) * ZP + ks * 32 + q * 8);
#pragma unroll
            for (int mt = 0; mt < 4; ++mt)
#pragma unroll
                for (int tj = 0; tj < 2; ++tj)
                    acc[mt][tj] = MFMA16(a[mt], w2pp[ks][tj], acc[mt][tj]);
        }
        if (f32out) {
#pragma unroll
            for (int tj = 0; tj < 2; ++tj) {
                int c = w * 32 + tj * 16 + t;
                float bias = fb[FB_IB2 + c];
#pragma unroll
                for (int mt = 0; mt < 4; ++mt)
#pragma unroll
                    for (int i = 0; i < 4; ++i)
                        ((float*)out)[((long)b * 64 + mt * 16 + q * 4 + i) * 128 + c] = acc[mt][tj][i] + bias;
            }
        } else {
#pragma unroll
            for (int tj = 0; tj < 2; ++tj) {
                int c = w * 32 + tj * 16 + t;
                float bias = fb[FB_IB2 + c];
#pragma unroll
                for (int mt = 0; mt < 4; ++mt)
#pragma unroll
                    for (int i = 0; i < 4; ++i)
                        ((short*)out)[((long)b * 64 + mt * 16 + q * 4 + i) * 128 + c] = f2b(acc[mt][tj][i] + bias);
            }
        }
    }
}

extern "C" void kernel_launch(void* const* d_in, const int* in_sizes, int n_in,
                              void* d_out, int out_size, void* d_ws, size_t ws_size,
                              hipStream_t stream) {
    const void* obs = d_in[0];
    const void* w1  = d_in[1];
    const void* b1  = d_in[2];
    const void* w2  = d_in[3];
    const void* b2  = d_in[4];
    const void* wq  = d_in[5];
    const void* bq  = d_in[6];
    const void* wo  = d_in[7];
    const void* bo  = d_in[8];
    const void* wi1 = d_in[9];
    const void* bi1 = d_in[10];
    const void* lg  = d_in[11];
    const void* lb  = d_in[12];
    const void* wi2 = d_in[13];
    const void* bi2 = d_in[14];
    int* flag = (int*)d_ws;
    short* wt = (short*)d_ws + 128;
    float* fb = (float*)((short*)d_ws + 128 + WT_TOTAL);
    short* obs_bf = (short*)d_ws + 128 + WT_TOTAL + 2 * FB_TOTAL;
    const bool big = (ws_size >= WS_NEEDED);

    if (big) {
        prep<true><<<dim3(16901), dim3(256), 0, stream>>>(
            obs, w1, w2, wq, wo, wi1, wi2, b1, b2, bq, bo, bi1, lg, lb, bi2,
            flag, wt, fb, obs_bf);
        macs_main<true><<<dim3(4096), dim3(256), 0, stream>>>(obs, flag, wt, fb, obs_bf, d_out);
    } else {
        prep<false><<<dim3(517), dim3(256), 0, stream>>>(
            obs, w1, w2, wq, wo, wi1, wi2, b1, b2, bq, bo, bi1, lg, lb, bi2,
            flag, wt, fb, obs_bf);
        macs_main<false><<<dim3(4096), dim3(256), 0, stream>>>(obs, flag, wt, fb, obs_bf, d_out);
    }
}